// Round 6
// baseline (47.000 us; speedup 1.0000x reference)
//
#include <hip/hip_runtime.h>

// Problem shape (fixed): U[8,64,256,256] f32, theta[8,2,65536] f32, out 256x256.
// Output [N,C,256,256] f32 == flat [N*HWo, C] buffer (reference's im_flat view).
constexpr int N   = 8;
constexpr int C   = 64;
constexpr int H   = 256;
constexpr int W   = 256;
constexpr int OH  = 256;
constexpr int OW  = 256;
constexpr int HWo = OH * OW;
constexpr int SPT = 4;                                  // samples per thread
constexpr int BLOCK = 256;
constexpr int GRID  = (N * HWo / SPT) * 16 / BLOCK;     // 8192
constexpr int GRID_PER_XCD = GRID / 8;                  // 1024 = one image per XCD

typedef float f32x4 __attribute__((ext_vector_type(4)));

// 16 lanes per sample-quad; each lane owns 4 channels (float4) of all 4 samples.
// 4 samples/thread -> 16 independent 16B gathers in flight (2x MLP vs R5's 8).
// XCD swizzle keeps each XCD's L2 on a single 16.7 MB image.
__global__ __launch_bounds__(256) void stn_kernel(
    const float* __restrict__ U,
    const float* __restrict__ theta,
    float* __restrict__ out)
{
    const int b  = blockIdx.x;
    const int bs = (b & 7) * GRID_PER_XCD + (b >> 3);   // bijective (GRID % 8 == 0)

    const int t  = bs * BLOCK + threadIdx.x;
    const int q  = t >> 4;              // sample-quad index
    const int cg = (t & 15) << 2;       // channel base: 0,4,...,60

    const int s0  = q << 2;             // first sample of quad
    const int n   = s0 >> 16;           // image index (HWo = 65536)
    const int p0  = s0 & (HWo - 1);     // ow0 multiple of 4 -> quad shares a row
    const int ow0 = p0 & (OW - 1);
    const int oh0 = p0 >> 8;

    // theta for all 4 samples: adjacent + 16B-aligned -> one float4 per component
    const f32x4 tx = *(const f32x4*)(theta + (size_t)(n * 2 + 0) * HWo + p0);
    const f32x4 ty = *(const f32x4*)(theta + (size_t)(n * 2 + 1) * HWo + p0);

    // identity grid: linspace(-1,1,256)[i] = i*(2/255) - 1
    const float gy   = (float)oh0 * (2.0f / 255.0f) - 1.0f;
    const int   base = n * (H * W);

    int   idx[SPT][4];
    float wgt[SPT][4];
#pragma unroll
    for (int k = 0; k < SPT; ++k) {
        const float gx = (float)(ow0 + k) * (2.0f / 255.0f) - 1.0f;
        // pixel coords: (v + 1) * (dim-1)/2
        const float x = (tx[k] + gx + 1.0f) * 127.5f;
        const float y = (ty[k] + gy + 1.0f) * 127.5f;
        // faithful: int-cast then clip; extrapolation weights kept as-is
        const int x0 = min(max((int)floorf(x), 0), W - 2);
        const int x1 = min(max((int)ceilf(x),  0), W - 1);
        const int y0 = min(max((int)floorf(y), 0), H - 2);
        const int y1 = min(max((int)ceilf(y),  0), H - 1);
        idx[k][0] = (base + y0 * W + x0) * C + cg;
        idx[k][1] = (base + y1 * W + x0) * C + cg;
        idx[k][2] = (base + y0 * W + x1) * C + cg;
        idx[k][3] = (base + y1 * W + x1) * C + cg;
        const float dx1 = (float)x1 - x, dx0 = x - (float)x0;
        const float dy1 = (float)y1 - y, dy0 = y - (float)y0;
        wgt[k][0] = dx1 * dy1;
        wgt[k][1] = dx1 * dy0;
        wgt[k][2] = dx0 * dy1;
        wgt[k][3] = dx0 * dy0;
    }

    // issue all 16 independent gathers back-to-back (max outstanding misses)
    f32x4 v[SPT][4];
#pragma unroll
    for (int k = 0; k < SPT; ++k)
#pragma unroll
        for (int j = 0; j < 4; ++j)
            v[k][j] = *(const f32x4*)(U + idx[k][j]);

    float* outp = out + (size_t)s0 * C + cg;
#pragma unroll
    for (int k = 0; k < SPT; ++k) {
        const f32x4 o = wgt[k][0] * v[k][0] + wgt[k][1] * v[k][1]
                      + wgt[k][2] * v[k][2] + wgt[k][3] * v[k][3];
        __builtin_nontemporal_store(o, (f32x4*)(outp + k * C));
    }
}

extern "C" void kernel_launch(void* const* d_in, const int* in_sizes, int n_in,
                              void* d_out, int out_size, void* d_ws, size_t ws_size,
                              hipStream_t stream)
{
    const float* U     = (const float*)d_in[0];
    const float* theta = (const float*)d_in[1];
    float* out         = (float*)d_out;

    stn_kernel<<<GRID, BLOCK, 0, stream>>>(U, theta, out);
}